// Round 3
// baseline (449.787 us; speedup 1.0000x reference)
//
#include <hip/hip_runtime.h>

// Fused 3D window attention (Swin-style) + 1x1 conv for MI355X (gfx950).
// One workgroup (256 thr = 4 waves) per 4x4x4 window; 4096 windows.
// Register-resident attention: QKV produced directly in MFMA-fragment
// orientation (q,k transposed / v normal), S^T,PV,conv chained via
// zero-padded K=32 MFMAs (k16 semantics). LDS: x-tile 16K overlaid by
// attn-out 20K, conflict-free stride-20 b64 layout. 3 barriers.

#define DD0 30
#define HH0 62
#define WW0 126
#define SD 7812      // HH0*WW0
#define SC 234360    // DD0*SD

typedef __bf16 bfx8 __attribute__((ext_vector_type(8)));
typedef float  fx4  __attribute__((ext_vector_type(4)));
typedef float  fx2  __attribute__((ext_vector_type(2)));

__device__ __forceinline__ fx4 MFMA(bfx8 a, bfx8 b, fx4 c) {
    return __builtin_amdgcn_mfma_f32_16x16x32_bf16(a, b, c, 0, 0, 0);
}
__device__ __forceinline__ fx4 fzero4() { fx4 v = {0.f, 0.f, 0.f, 0.f}; return v; }

// k16-semantics MFMA: both operands hold 4 values at k=quad*4+j, placed in
// j=0..3 of each quad's k-chunk, upper half zero => contracts exactly 16 k.
__device__ __forceinline__ fx4 MFMA16(uint2 a, uint2 b, fx4 c) {
    uint4 ua; ua.x = a.x; ua.y = a.y; ua.z = 0u; ua.w = 0u;
    uint4 ub; ub.x = b.x; ub.y = b.y; ub.z = 0u; ub.w = 0u;
    return MFMA(__builtin_bit_cast(bfx8, ua), __builtin_bit_cast(bfx8, ub), c);
}
__device__ __forceinline__ unsigned pk2(float a, float b) {
    __bf16 ax = (__bf16)a, by = (__bf16)b;
    unsigned short ua = __builtin_bit_cast(unsigned short, ax);
    unsigned short ub = __builtin_bit_cast(unsigned short, by);
    return (unsigned)ua | ((unsigned)ub << 16);
}

// Bq: row-major qkv_w (identity copy) -> K=32 W-frag layout.
// Bc2[((h*4+kq)*128 + o)*4 + j] = conv_w[o][(h*4+kq)*4 + j]  (k16 A-frags).
__global__ void prep_kernel(const float* __restrict__ qkv_w,
                            const float* __restrict__ conv_w,
                            __bf16* __restrict__ Bq, __bf16* __restrict__ Bc2) {
    const int i = blockIdx.x * 256 + threadIdx.x;   // 65536 exactly
    if (i < 49152) {
        Bq[i] = (__bf16)qkv_w[i];
    } else {
        const int t = i - 49152;                    // 0..16383
        const int o  = (t >> 2) & 127;
        const int ch = ((t >> 9) << 2) | (t & 3);
        Bc2[t] = (__bf16)conv_w[o * 128 + ch];
    }
}

__global__ __launch_bounds__(256, 4) void winattn_kernel(
    const float* __restrict__ x,
    const float* __restrict__ qkv_b,
    const float* __restrict__ conv_b,
    const __bf16* __restrict__ Bq,
    const __bf16* __restrict__ Bc2,
    float* __restrict__ out)
{
    // 20.5 KB LDS: x-tile [64][128] bf16 (16K) overlaid by attn-out
    // ldsO[8 heads][64 tok][20] bf16 (20480 B). x dead before first O write.
    __shared__ __align__(16) unsigned char lds_raw[20480];
    __bf16* ldsX = (__bf16*)lds_raw;
    __bf16* ldsO = (__bf16*)lds_raw;

    const int tid  = threadIdx.x;
    const int wave = tid >> 6;
    const int lane = tid & 63;
    const int quad = lane >> 4;
    const int l15  = lane & 15;

    // XCD swizzle: contiguous 512-window slab per XCD (W-adjacent L2-local).
    const int blk = blockIdx.x;
    const int wid = ((blk & 7) << 9) | (blk >> 3);
    const int Db = (wid >> 9) << 2;
    const int Hb = ((wid >> 5) & 15) << 2;
    const int Wb = (wid & 31) << 2;

    // pad-mask bit per token (token index == lane)
    unsigned long long pmask;
    {
        const bool p = (Db + (lane >> 4) >= DD0) || (Hb + ((lane >> 2) & 3) >= HH0) ||
                       (Wb + (lane & 3) >= WW0);
        pmask = __ballot(p);
    }

    // ---- stage x window tile -> ldsX, swizzle phys_chunk = (c>>3) ^ (tok&15) ----
    {
        #pragma unroll
        for (int it = 0; it < 16; it++) {
            const int u = it * 256 + tid;          // (c, dh, wpair)
            const int wp = u & 1;
            const int dh = (u >> 1) & 15;
            const int c  = u >> 5;
            const int Dg = Db + (dh >> 2), Hg = Hb + (dh & 3);
            const bool valid = (Dg < DD0) && (Hg < HH0) && (wp == 0 || Wb < 124);
            fx2 v = {0.f, 0.f};
            if (valid) v = *(const fx2*)(x + c * SC + Dg * SD + Hg * WW0 + Wb + wp * 2);
            const int tok0 = dh * 4 + wp * 2;
            ldsX[tok0 * 128 + (((c >> 3) ^ (tok0 & 15)) << 3) + (c & 7)] = (__bf16)v[0];
            const int tok1 = tok0 + 1;
            ldsX[tok1 * 128 + (((c >> 3) ^ (tok1 & 15)) << 3) + (c & 7)] = (__bf16)v[1];
        }
    }
    __syncthreads();   // b1

    // ---- QKV: wave-private heads h0=wave, h1=wave+4.
    //  q,k transposed: mfma(A=Wfrag, B=Xfrag) -> C'[col][tok] (col=4q+r, tok=l15)
    //  v normal:       mfma(A=Xfrag, B=Wfrag) -> C[tok][elem] (tok=4q+r, elem=l15)
    // Resulting packed frags feed k16 MFMAs with zero data movement.
    uint2 qf[2][4], kf[2][4], vf[2][4];   // [hi][tile]
    #pragma unroll
    for (int pair = 0; pair < 2; pair++) {
        bfx8 X[2][4];
        #pragma unroll
        for (int t = 0; t < 2; t++)
            #pragma unroll
            for (int kk = 0; kk < 4; kk++) {
                const int m = (pair * 2 + t) * 16 + l15;
                const int phys = (kk * 4 + quad) ^ (m & 15);
                X[t][kk] = *(const bfx8*)(ldsX + m * 128 + phys * 8);
            }
        #pragma unroll
        for (int s = 0; s < 6; s++) {
            const int hi = s >> 1 >= 1 ? (s >= 3 ? 1 : 0) : 0;   // s<3 -> hi 0
            const int kind = s < 3 ? s : s - 3;                  // 0=q,1=k,2=v
            const int h = wave + ((s < 3) ? 0 : 4);
            const int colbase = kind * 128 + h * 16;
            fx4 acc[2];
            acc[0] = fzero4(); acc[1] = fzero4();
            #pragma unroll
            for (int kk = 0; kk < 4; kk++) {
                const bfx8 Wf = *(const bfx8*)(Bq + ((colbase + l15) * 16 + kk * 4 + quad) * 8);
                #pragma unroll
                for (int t = 0; t < 2; t++)
                    acc[t] = (kind == 2) ? MFMA(X[t][kk], Wf, acc[t])
                                         : MFMA(Wf, X[t][kk], acc[t]);
            }
            const int hidx = (s < 3) ? 0 : 1;
            #pragma unroll
            for (int t = 0; t < 2; t++) {
                const int tile = pair * 2 + t;
                if (kind == 2) {           // v: bias by elem = l15
                    const float b = qkv_b[colbase + l15];
                    uint2 f;
                    f.x = pk2(acc[t][0] + b, acc[t][1] + b);
                    f.y = pk2(acc[t][2] + b, acc[t][3] + b);
                    vf[hidx][tile] = f;
                } else {                   // q/k: bias by col = 4*quad+r
                    float v0 = acc[t][0] + qkv_b[colbase + 4 * quad + 0];
                    float v1 = acc[t][1] + qkv_b[colbase + 4 * quad + 1];
                    float v2 = acc[t][2] + qkv_b[colbase + 4 * quad + 2];
                    float v3 = acc[t][3] + qkv_b[colbase + 4 * quad + 3];
                    if (kind == 0) { v0 *= 0.25f; v1 *= 0.25f; v2 *= 0.25f; v3 *= 0.25f; }
                    uint2 f;
                    f.x = pk2(v0, v1);
                    f.y = pk2(v2, v3);
                    if (kind == 0) qf[hidx][tile] = f; else kf[hidx][tile] = f;
                }
            }
        }
    }
    __syncthreads();   // b2: all x reads done; region becomes ldsO

    // masks: mB[tau] by tok_m = 16*tau + l15; mA[nu] r-bits by tok_n = 16*nu+4*quad+r
    unsigned mBv[4], mAv[4];
    #pragma unroll
    for (int i = 0; i < 4; i++) {
        mBv[i] = (unsigned)((pmask >> (16 * i + l15)) & 1ull);
        mAv[i] = (unsigned)((pmask >> (16 * i + 4 * quad)) & 0xFull);
    }

    // ---- attention per head: S^T = mfma16(kf, qf); softmax; O^T = mfma16(vf, pf) ----
    #pragma unroll
    for (int hi = 0; hi < 2; hi++) {
        const int h = wave + hi * 4;
        fx4 ot[4];
        #pragma unroll
        for (int i = 0; i < 4; i++) ot[i] = fzero4();
        #pragma unroll
        for (int tau = 0; tau < 4; tau++) {
            fx4 stc[4];
            #pragma unroll
            for (int nu = 0; nu < 4; nu++)
                stc[nu] = MFMA16(kf[hi][nu], qf[hi][tau], fzero4());
            // masked exp + row-sum over tok_n (no max-sub: logits O(1))
            float sum = 0.f;
            const unsigned bm = mBv[tau];
            #pragma unroll
            for (int nu = 0; nu < 4; nu++)
                #pragma unroll
                for (int r = 0; r < 4; r++) {
                    const unsigned am = (mAv[nu] >> r) & 1u;
                    const float e = (am ^ bm) ? 0.f : __expf(stc[nu][r]);
                    stc[nu][r] = e;
                    sum += e;
                }
            sum += __shfl_xor(sum, 16);
            sum += __shfl_xor(sum, 32);
            const float rinv = __builtin_amdgcn_rcpf(sum);
            #pragma unroll
            for (int nu = 0; nu < 4; nu++) {
                uint2 pf;
                pf.x = pk2(stc[nu][0] * rinv, stc[nu][1] * rinv);
                pf.y = pk2(stc[nu][2] * rinv, stc[nu][3] * rinv);
                ot[tau] = MFMA16(vf[hi][nu], pf, ot[tau]);
            }
        }
        // O^T[elem=4q+r][tok=16tau+l15] -> ldsO[h][tok][elem], stride 20 (conflict-free b64)
        #pragma unroll
        for (int tau = 0; tau < 4; tau++) {
            uint2 w;
            w.x = pk2(ot[tau][0], ot[tau][1]);
            w.y = pk2(ot[tau][2], ot[tau][3]);
            *(uint2*)(ldsO + h * 1280 + (16 * tau + l15) * 20 + 4 * quad) = w;
        }
    }
    __syncthreads();   // b3

    // ---- conv: C[o][tok] = sum_h mfma16(Wc-frag, O-frag); wave owns 32 o ----
    {
        fx4 cacc[2][4];
        #pragma unroll
        for (int t = 0; t < 2; t++)
            #pragma unroll
            for (int nt = 0; nt < 4; nt++) cacc[t][nt] = fzero4();
        #pragma unroll
        for (int h = 0; h < 8; h++) {
            uint2 bfr[4], afr[2];
            #pragma unroll
            for (int nt = 0; nt < 4; nt++)
                bfr[nt] = *(const uint2*)(ldsO + h * 1280 + (16 * nt + l15) * 20 + 4 * quad);
            #pragma unroll
            for (int t = 0; t < 2; t++)
                afr[t] = *(const uint2*)(Bc2 + (((h * 4 + quad) * 128) + (wave * 2 + t) * 16 + l15) * 4);
            #pragma unroll
            for (int t = 0; t < 2; t++)
                #pragma unroll
                for (int nt = 0; nt < 4; nt++)
                    cacc[t][nt] = MFMA16(afr[t], bfr[nt], cacc[t][nt]);
        }
        // stores: lane holds o = (wave*2+t)*16 + 4*quad + r at tok = 16*nt + l15
        const int bh = l15 >> 2, bw = l15 & 3;
        float cb[2][4];
        #pragma unroll
        for (int t = 0; t < 2; t++)
            #pragma unroll
            for (int r = 0; r < 4; r++)
                cb[t][r] = conv_b[(wave * 2 + t) * 16 + 4 * quad + r];
        #pragma unroll
        for (int nt = 0; nt < 4; nt++) {
            const int Dg = Db + nt;
            const bool ok = (Dg < DD0) && (Hb + bh < HH0) && (Wb + bw < WW0);
            if (!ok) continue;
            const int base_sp = Dg * SD + (Hb + bh) * WW0 + (Wb + bw);
            #pragma unroll
            for (int t = 0; t < 2; t++) {
                const int o0 = (wave * 2 + t) * 16 + 4 * quad;
                #pragma unroll
                for (int r = 0; r < 4; r++)
                    out[(o0 + r) * SC + base_sp] = cacc[t][nt][r] + cb[t][r];
            }
        }
    }
}

extern "C" void kernel_launch(void* const* d_in, const int* in_sizes, int n_in,
                              void* d_out, int out_size, void* d_ws, size_t ws_size,
                              hipStream_t stream) {
    const float* x      = (const float*)d_in[0];
    const float* qkv_w  = (const float*)d_in[1];
    const float* qkv_b  = (const float*)d_in[2];
    const float* conv_w = (const float*)d_in[3];
    const float* conv_b = (const float*)d_in[4];
    float* out = (float*)d_out;

    __bf16* Bq  = (__bf16*)d_ws;                      // 49152 bf16
    __bf16* Bc2 = (__bf16*)((char*)d_ws + 98304);     // 16384 bf16

    prep_kernel<<<256, 256, 0, stream>>>(qkv_w, conv_w, Bq, Bc2);
    winattn_kernel<<<4096, 256, 0, stream>>>(x, qkv_b, conv_b, Bq, Bc2, out);
}